// Round 14
// baseline (1274.730 us; speedup 1.0000x reference)
//
#include <hip/hip_runtime.h>
#include <hip/hip_fp8.h>
#include <cstdint>

typedef _Float16 f16;
typedef _Float16 f16x2 __attribute__((ext_vector_type(2)));
typedef _Float16 f16x4 __attribute__((ext_vector_type(4)));
typedef _Float16 f16x8 __attribute__((ext_vector_type(8)));
typedef float    f32x4 __attribute__((ext_vector_type(4)));
typedef __hip_fp8_e4m3 fp8;
typedef long     i64;
typedef unsigned char u8;

#define BATCH 8
#define NSEQ  1800
#define DIM   512
#define NMASK 900
#define MROWS 14400   // BATCH*NSEQ
#define MMASK 7200    // BATCH*NMASK

// ---------------- async 16B global->LDS (with fallback) ----------------
__device__ __forceinline__ void stage16(const void* g, void* lds_wave_base, int lane) {
#if __has_builtin(__builtin_amdgcn_global_load_lds)
  (void)lane;
  __builtin_amdgcn_global_load_lds((const __attribute__((address_space(1))) void*)g,
                                   (__attribute__((address_space(3))) void*)lds_wave_base,
                                   16, 0, 0);
#else
  ((uint4*)lds_wave_base)[lane] = *(const uint4*)g;
#endif
}

__device__ __forceinline__ float gelu_f(float x) {
  // tanh-approx gelu (jax.nn.gelu approximate=True)
  float x3 = x * x * x;
  float y  = 0.7978845608028654f * (x + 0.044715f * x3);
  float t;
  if (y > 15.f)       t = 1.f;
  else if (y < -15.f) t = -1.f;
  else { float e = __expf(2.f * y); t = (e - 1.f) / (e + 1.f); }
  return 0.5f * x * (1.f + t);
}

// ---------------- mask scatter (+ gathered row table for layer-3 compaction) ----------------
__global__ void scatter_mask(const int* __restrict__ mi, int* __restrict__ maskf,
                             int* __restrict__ grows) {
  int i = blockIdx.x * 256 + threadIdx.x;
  if (i < BATCH * NMASK) {
    int b = i / NMASK;
    int row = b * NSEQ + mi[i];
    maskf[row] = 1;
    grows[i] = row;
  }
}

// ---------------- weight transpose + fp8 convert: in[K,N] -> out[N,K] ----------------
__global__ void transposeW(const float* __restrict__ in, fp8* __restrict__ out, int K, int N) {
  long off = (long)blockIdx.z * K * N;
  const float* ip = in + off;
  fp8* op = out + off;
  __shared__ float tile[32][33];
  int n0 = blockIdx.x * 32, k0 = blockIdx.y * 32;
  int tx = threadIdx.x, ty = threadIdx.y;  // (32,8)
#pragma unroll
  for (int i = 0; i < 4; ++i)
    tile[ty + 8 * i][tx] = ip[(long)(k0 + ty + 8 * i) * N + n0 + tx];
  __syncthreads();
#pragma unroll
  for (int i = 0; i < 4; ++i)
    op[(long)(n0 + ty + 8 * i) * K + k0 + tx] = fp8(tile[tx][ty + 8 * i]);
}

// ---------------- patch embed + pos/val emb + mask token -> x0 (f16 residual) ----------------
__global__ __launch_bounds__(256)
void prep_kernel(const float* __restrict__ img, const float* __restrict__ pos_table,
                 const float* __restrict__ val_table, const float* __restrict__ patch_W,
                 const float* __restrict__ patch_b, const float* __restrict__ mask_tok,
                 const int* __restrict__ valid_len, const int* __restrict__ maskf,
                 float* __restrict__ patches, f16* __restrict__ x0) {
  int n = blockIdx.x;       // 0..1799
  int b = blockIdx.y;       // 0..7
  int t = threadIdx.x;
  __shared__ float p[6];
  int h = n / 75, ws = n % 75;
  if (t < 6) {
    int pp = t / 3, c = t % 3;
    float v = img[((b * 3 + c) * 24 + h) * 150 + ws * 2 + pp];
    p[t] = v;
    patches[((long)b * NSEQ + n) * 6 + t] = v;
  }
  __syncthreads();
  int vl = valid_len[b];
  if (vl == 150) vl = 149;
  int nv = (vl + 1) >> 1;          // ceil(vl/2)
  int seg = (ws < nv) ? 1 : 0;
  bool masked = maskf[b * NSEQ + n] != 0;
  for (int d = t; d < DIM; d += 256) {
    float pos = pos_table[(long)(n + 1) * DIM + d] + val_table[seg * DIM + d];
    float v;
    if (masked) {
      v = mask_tok[d] + pos;
    } else {
      float acc = patch_b[d] + pos;
#pragma unroll
      for (int j = 0; j < 6; ++j) acc += p[j] * patch_W[j * DIM + d];
      v = acc;
    }
    x0[((long)b * NSEQ + n) * DIM + d] = (f16)v;
  }
}

// ---------------- LayerNorm: 8 rows/block, 1 row/wave-pass, no LDS ----------------
__global__ __launch_bounds__(256)
void ln_kernel(const f16* __restrict__ x, const float* __restrict__ s,
               const float* __restrict__ bb, fp8* __restrict__ out) {
  const int t = threadIdx.x;
  const int wave = t >> 6, lane = t & 63;
  const int col = lane * 8;
  float sv[8], bv[8];
  {
    float4 s0 = *(const float4*)&s[col], s1 = *(const float4*)&s[col + 4];
    float4 b0 = *(const float4*)&bb[col], b1 = *(const float4*)&bb[col + 4];
    sv[0] = s0.x; sv[1] = s0.y; sv[2] = s0.z; sv[3] = s0.w;
    sv[4] = s1.x; sv[5] = s1.y; sv[6] = s1.z; sv[7] = s1.w;
    bv[0] = b0.x; bv[1] = b0.y; bv[2] = b0.z; bv[3] = b0.w;
    bv[4] = b1.x; bv[5] = b1.y; bv[6] = b1.z; bv[7] = b1.w;
  }
  long rowBase = (long)blockIdx.x * 8 + wave * 2;
#pragma unroll
  for (int rr = 0; rr < 2; ++rr) {
    long row = rowBase + rr;
    f16x8 v = *(const f16x8*)(x + row * DIM + col);
    float f[8], sum = 0.f, sq = 0.f;
#pragma unroll
    for (int j = 0; j < 8; ++j) { f[j] = (float)v[j]; sum += f[j]; sq += f[j] * f[j]; }
#pragma unroll
    for (int mk = 1; mk < 64; mk <<= 1) {
      sum += __shfl_xor(sum, mk);
      sq  += __shfl_xor(sq, mk);
    }
    float mean = sum * (1.f / DIM);
    float var  = sq * (1.f / DIM) - mean * mean;
    float rstd = rsqrtf(var + 1e-5f);
    fp8 o8[8];
#pragma unroll
    for (int j = 0; j < 8; ++j) o8[j] = fp8((f[j] - mean) * rstd * sv[j] + bv[j]);
    *(uint2*)&out[row * DIM + col] = *(const uint2*)o8;
  }
}

// ---------------- MFMA fp8 GEMM 128x128, 8 waves (small-N GEMMs + layer-3 compact) ----
// R13: same 128^2 tile and block count as before (452 blocks preserves the
// inter-block drain overlap per R10), but 512 threads / 8 waves per block:
// waves/CU doubles ~7 -> ~14 to hide the vmcnt(0) barrier drains (R12/R13
// occupancy mechanism). Per-wave acc halves to [4][2]; k-summation order per
// output element unchanged -> bit-identical. Each wave stages its own c16 =
// wave chunk (2 A + 2 B loads). gidx: gather for layer-3 compaction.
// EPI 1: bias + f16 residual -> f16.
template <int EPI>
__global__ __launch_bounds__(512, 4)
void gemm8_kernel(const u8* __restrict__ A, const u8* __restrict__ Bt,
                  const float* __restrict__ bias, const f16* __restrict__ res,
                  f16* __restrict__ outH, fp8* __restrict__ out8,
                  const int* __restrict__ gidx,
                  int M, int N, int K, int gx) {
  __shared__ u8 As[8 * 128 * 16];   // 16 KB
  __shared__ u8 Bs[8 * 128 * 16];   // 16 KB
  const int tid  = threadIdx.x;
  const int wave = tid >> 6, lane = tid & 63;   // wave 0..7
  const int quad = lane >> 4, l16 = lane & 15;
  const int wm = wave >> 1, wn = wave & 1;      // wm 0..3 (32-row slab), wn 0..1

  const int nwg = (int)gridDim.x;
  const int q = nwg >> 3, rr = nwg & 7;
  const int xcd = (int)blockIdx.x & 7, idx = (int)blockIdx.x >> 3;
  const int wg = (xcd < rr ? xcd * (q + 1) : rr * (q + 1) + (xcd - rr) * q) + idx;
  const long rowBase = (long)(wg / gx) * 128;
  const long colBase = (long)(wg % gx) * 128;

  f32x4 acc[4][2];   // [ni][mi]
  f32x4 zero = {0.f, 0.f, 0.f, 0.f};
#pragma unroll
  for (int ni = 0; ni < 4; ++ni)
#pragma unroll
    for (int mi = 0; mi < 2; ++mi) acc[ni][mi] = zero;

  long rA0 = rowBase + lane;       if (rA0 > M - 1) rA0 = M - 1;
  long rA1 = rowBase + 64 + lane;  if (rA1 > M - 1) rA1 = M - 1;
  if (gidx) { rA0 = gidx[rA0]; rA1 = gidx[rA1]; }
  const u8* Arow0 = A + rA0 * K + wave * 16;    // c16 = wave
  const u8* Arow1 = A + rA1 * K + wave * 16;
  const u8* Brow0 = Bt + (colBase + lane) * K + wave * 16;
  const u8* Brow1 = Bt + (colBase + 64 + lane) * K + wave * 16;
  u8* AsC0 = As + wave * 2048;              // c16=wave, rows 0-63
  u8* AsC1 = AsC0 + 64 * 16;                // rows 64-127
  u8* BsC0 = Bs + wave * 2048;
  u8* BsC1 = BsC0 + 64 * 16;

  for (int kt = 0; kt < K; kt += 128) {
    __syncthreads();
    stage16(Arow0 + kt, AsC0, lane);
    stage16(Arow1 + kt, AsC1, lane);
    stage16(Brow0 + kt, BsC0, lane);
    stage16(Brow1 + kt, BsC1, lane);
    __syncthreads();
#pragma unroll
    for (int ks = 0; ks < 4; ++ks) {
      const int cb = (2 * ks + (quad >> 1)) * 2048 + (quad & 1) * 8;
      i64 af[2], bf[4];
#pragma unroll
      for (int mi = 0; mi < 2; ++mi)
        af[mi] = *(const i64*)&As[cb + (wm * 32 + mi * 16 + l16) * 16];
#pragma unroll
      for (int ni = 0; ni < 4; ++ni)
        bf[ni] = *(const i64*)&Bs[cb + (wn * 64 + ni * 16 + l16) * 16];
#pragma unroll
      for (int ni = 0; ni < 4; ++ni)
#pragma unroll
        for (int mi = 0; mi < 2; ++mi)
          acc[ni][mi] = __builtin_amdgcn_mfma_f32_16x16x32_fp8_fp8(bf[ni], af[mi], acc[ni][mi], 0, 0, 0);
    }
  }

#pragma unroll
  for (int mi = 0; mi < 2; ++mi) {
    long m = rowBase + wm * 32 + mi * 16 + l16;
    if (m < M) {
      long gm = gidx ? (long)gidx[m] : m;
#pragma unroll
      for (int ni = 0; ni < 4; ++ni) {
        long n = colBase + wn * 64 + ni * 16 + quad * 4;
        float4 bv = *(const float4*)&bias[n];
        f32x4 v = acc[ni][mi];
        v[0] += bv.x; v[1] += bv.y; v[2] += bv.z; v[3] += bv.w;
        long o = m * N + n;
        if (EPI == 1) {
          f16x4 rr4 = *(const f16x4*)&res[gm * N + n];
          f16x4 ov;
#pragma unroll
          for (int r = 0; r < 4; ++r) ov[r] = (f16)(v[r] + (float)rr4[r]);
          *(f16x4*)&outH[o] = ov;
        } else if (EPI == 2) {
          fp8 hv[4];
#pragma unroll
          for (int r = 0; r < 4; ++r) hv[r] = fp8(gelu_f(v[r]));
          *(uint32_t*)&out8[o] = *(const uint32_t*)hv;
        } else {
          f16x4 hv;
#pragma unroll
          for (int r = 0; r < 4; ++r) hv[r] = (f16)v[r];
          *(f16x4*)&outH[o] = hv;
        }
      }
    }
  }
}

// ---------------- MFMA fp8 GEMM 256x128, 8 waves (large-N GEMMs: QKV, W1) ----
// Only used where grid >= ~2x CU count (QKV: 684 blocks, W1: 912 blocks).
// EPI 0: bias -> f16 (+outV: V-cols n>=1024 transposed to Vt);
// EPI 2: bias + gelu -> fp8.
template <int EPI>
__global__ __launch_bounds__(512)
void gemm256_kernel(const u8* __restrict__ A, const u8* __restrict__ Bt,
                    const float* __restrict__ bias,
                    f16* __restrict__ outH, fp8* __restrict__ out8, f16* __restrict__ outV,
                    int M, int N, int K, int gx) {
  __shared__ u8 As[8 * 256 * 16];   // 32 KB
  __shared__ u8 Bs[8 * 128 * 16];   // 16 KB
  const int tid  = threadIdx.x;
  const int wave = tid >> 6, lane = tid & 63;
  const int quad = lane >> 4, l16 = lane & 15;
  const int wm = wave >> 1, wn = wave & 1;   // wm 0..3, wn 0..1

  const int nwg = (int)gridDim.x;
  const int q = nwg >> 3, rr = nwg & 7;
  const int xcd = (int)blockIdx.x & 7, idx = (int)blockIdx.x >> 3;
  const int wg = (xcd < rr ? xcd * (q + 1) : rr * (q + 1) + (xcd - rr) * q) + idx;
  const long rowBase = (long)(wg / gx) * 256;
  const long colBase = (long)(wg % gx) * 128;

  f32x4 acc[4][4];   // [ni][mi]
  f32x4 zero = {0.f, 0.f, 0.f, 0.f};
#pragma unroll
  for (int ni = 0; ni < 4; ++ni)
#pragma unroll
    for (int mi = 0; mi < 4; ++mi) acc[ni][mi] = zero;

  const u8* ArowP[4];
#pragma unroll
  for (int i = 0; i < 4; ++i) {
    long r = rowBase + i * 64 + lane;
    if (r > M - 1) r = M - 1;
    ArowP[i] = A + r * K + wave * 16;
  }
  const u8* BrowP[2];
#pragma unroll
  for (int i = 0; i < 2; ++i)
    BrowP[i] = Bt + (colBase + i * 64 + lane) * K + wave * 16;
  u8* AsD = As + wave * 4096;
  u8* BsD = Bs + wave * 2048;

  for (int kt = 0; kt < K; kt += 128) {
    __syncthreads();
#pragma unroll
    for (int i = 0; i < 4; ++i)
      stage16(ArowP[i] + kt, AsD + i * 1024, lane);
#pragma unroll
    for (int i = 0; i < 2; ++i)
      stage16(BrowP[i] + kt, BsD + i * 1024, lane);
    __syncthreads();
#pragma unroll
    for (int ks = 0; ks < 4; ++ks) {
      const int c16 = 2 * ks + (quad >> 1);
      const int cbA = c16 * 4096 + (quad & 1) * 8;
      const int cbB = c16 * 2048 + (quad & 1) * 8;
      i64 af[4], bf[4];
#pragma unroll
      for (int mi = 0; mi < 4; ++mi)
        af[mi] = *(const i64*)&As[cbA + (wm * 64 + mi * 16 + l16) * 16];
#pragma unroll
      for (int ni = 0; ni < 4; ++ni)
        bf[ni] = *(const i64*)&Bs[cbB + (wn * 64 + ni * 16 + l16) * 16];
#pragma unroll
      for (int ni = 0; ni < 4; ++ni)
#pragma unroll
        for (int mi = 0; mi < 4; ++mi)
          acc[ni][mi] = __builtin_amdgcn_mfma_f32_16x16x32_fp8_fp8(bf[ni], af[mi], acc[ni][mi], 0, 0, 0);
    }
  }

  // ---- fused V-transpose path (QKV GEMM, V columns) ----
  if (EPI == 0 && outV != nullptr && colBase >= 1024) {
    const int hh = (int)((colBase - 1024) >> 6) + wn;   // 0..7
#pragma unroll
    for (int mi = 0; mi < 4; ++mi) {
      long m = rowBase + wm * 64 + mi * 16 + l16;
      if (m < M) {
        int b = (int)m / NSEQ;
        int key = (int)m - b * NSEQ;
        f16* vdst = outV + ((long)(b * 8 + hh) * 64) * NSEQ + key;
#pragma unroll
        for (int ni = 0; ni < 4; ++ni) {
          long n = colBase + wn * 64 + ni * 16 + quad * 4;
          float4 bv = *(const float4*)&bias[n];
          f32x4 v = acc[ni][mi];
#pragma unroll
          for (int r = 0; r < 4; ++r)
            vdst[(long)(ni * 16 + quad * 4 + r) * NSEQ] = (f16)(v[r] + (&bv.x)[r]);
        }
      }
    }
    return;
  }

#pragma unroll
  for (int mi = 0; mi < 4; ++mi) {
    long m = rowBase + wm * 64 + mi * 16 + l16;
    if (m < M) {
#pragma unroll
      for (int ni = 0; ni < 4; ++ni) {
        long n = colBase + wn * 64 + ni * 16 + quad * 4;
        float4 bv = *(const float4*)&bias[n];
        f32x4 v = acc[ni][mi];
        v[0] += bv.x; v[1] += bv.y; v[2] += bv.z; v[3] += bv.w;
        long o = m * N + n;
        if (EPI == 2) {
          fp8 hv[4];
#pragma unroll
          for (int r = 0; r < 4; ++r) hv[r] = fp8(gelu_f(v[r]));
          *(uint32_t*)&out8[o] = *(const uint32_t*)hv;
        } else {
          f16x4 hv;
#pragma unroll
          for (int r = 0; r < 4; ++r) hv[r] = (f16)v[r];
          *(f16x4*)&outH[o] = hv;
        }
      }
    }
  }
}

// ---------------- MFMA flash attention v8b: 8 waves x 16 q-rows (R13 verified) ----
#define ATTN_TILE_BODY(MASKV)                                                           \
  {                                                                                     \
    _Pragma("unroll")                                                                   \
    for (int n = 0; n < 4; ++n) {                                                       \
      f16x8 b0 = *(const f16x8*)&Ks[n * 16 + l16][quad * 8];                            \
      f16x8 b1 = *(const f16x8*)&Ks[n * 16 + l16][32 + quad * 8];                       \
      f32x4 zz = {0.f, 0.f, 0.f, 0.f};                                                  \
      zz = __builtin_amdgcn_mfma_f32_16x16x32_f16(qfA0, b0, zz, 0, 0, 0);               \
      zz = __builtin_amdgcn_mfma_f32_16x16x32_f16(qfA1, b1, zz, 0, 0, 0);               \
      bool bad = (MASKV) && (n > 0 || l16 >= 8);                                        \
      _Pragma("unroll")                                                                 \
      for (int r = 0; r < 4; ++r) {                                                     \
        float pp = exp2f(fmaf(zz[r], K1, -8.f));                                        \
        if (bad) pp = 0.f;                                                              \
        Ps[wave * 16 + quad * 4 + r][(n * 16 + l16) ^ (quad << 3)] = (f16)pp;           \
      }                                                                                 \
    }                                                                                   \
    {                                                                                   \
      f16x8 pa0 = *(const f16x8*)&Ps[wave * 16 + l16][pswz];                            \
      f16x8 pa1 = *(const f16x8*)&Ps[wave * 16 + l16][32 + pswz];                       \
      __builtin_amdgcn_s_setprio(1);                                                    \
      _Pragma("unroll")                                                                 \
      for (int nt = 0; nt < 4; ++nt) {                                                  \
        f16x8 vb0 = *(const f16x8*)&Vs[nt * 16 + l16][quad * 8];                        \
        f16x8 vb1 = *(const f16x8*)&Vs[nt * 16 + l16][32 + quad * 8];                   \
        oA[nt] = __builtin_amdgcn_mfma_f32_16x16x32_f16(pa0, vb0, oA[nt], 0, 0, 0);     \
        oA[nt] = __builtin_amdgcn_mfma_f32_16x16x32_f16(pa1, vb1, oA[nt], 0, 0, 0);     \
      }                                                                                 \
      lsaccA = __builtin_amdgcn_mfma_f32_16x16x32_f16(pa0, onesf, lsaccA, 0, 0, 0);     \
      lsaccA = __builtin_amdgcn_mfma_f32_16x16x32_f16(pa1, onesf, lsaccA, 0, 0, 0);     \
      __builtin_amdgcn_s_setprio(0);                                                    \
    }                                                                                   \
  }

__global__ __launch_bounds__(512, 4)
void attn_kernel(const f16* __restrict__ qkv, const f16* __restrict__ Vt,
                 fp8* __restrict__ out) {
  const int g = blockIdx.x;                  // 0..959
  const int hi = g / 120, rem = g % 120;     // 120 = 15 q-tiles * 8
  const int qt = rem >> 3;                   // 0..14
  const int bh = hi * 8 + (rem & 7);         // g%8 == bh&7 -> one XCD per bh
  const int b = bh >> 3, hh = bh & 7;
  const int t = threadIdx.x;                 // 0..511
  const int wave = t >> 6, lane = t & 63;    // wave 0..7
  const int quad = lane >> 4, l16 = lane & 15;
  const int q0 = qt * 128;
  const long baseBN = (long)b * NSEQ;
  const float K1 = 0.18033688011112042f;     // 0.125 * log2(e)
  const int pswz = ((quad ^ (l16 >> 2)) << 3);   // P-read swizzled col base
  const f16x8 onesf = {(f16)1.f, (f16)1.f, (f16)1.f, (f16)1.f,
                       (f16)1.f, (f16)1.f, (f16)1.f, (f16)1.f};

  __shared__ f16 Ks[64][80];    // [key][dh]
  __shared__ f16 Vs[64][80];    // [dh][key]
  __shared__ f16 Ps[128][80];   // [q%128][key], rows wave-private

  int qrA = q0 + wave * 16 + l16; if (qrA > NSEQ - 1) qrA = NSEQ - 1;
  const f16* QpA = qkv + (baseBN + qrA) * 1536 + hh * 64 + quad * 8;
  f16x8 qfA0 = *(const f16x8*)(QpA);
  f16x8 qfA1 = *(const f16x8*)(QpA + 32);

  f32x4 oA[4];
  f32x4 lsaccA = {0.f, 0.f, 0.f, 0.f};
#pragma unroll
  for (int nt = 0; nt < 4; ++nt) oA[nt] = f32x4{0, 0, 0, 0};

  const f16* Kg = qkv + baseBN * 1536 + hh * 64 + 512;
  const f16* Vg = Vt + (long)bh * 64 * 1800;
  const int sr = t >> 3, sc = t & 7;         // sr 0..63, sc 0..7
  const uint4 z4 = {0u, 0u, 0u, 0u};

  const f16* KgS = Kg + (long)sr * 1536 + sc * 8;
  const f16* VgS = Vg + (long)sr * 1800 + sc * 8;

  uint4 pk0 = *(const uint4*)(KgS);
  uint4 pv0 = *(const uint4*)(VgS);

  for (int kt = 0; kt < 28; ++kt) {          // tiles 0..27: no key masking
    __syncthreads();
    *(uint4*)&Ks[sr][sc * 8] = pk0;
    *(uint4*)&Vs[sr][sc * 8] = pv0;
    {
      long ko = (long)(kt + 1) * 64;
      pk0 = *(const uint4*)(KgS + ko * 1536);
      bool vok = (ko + sc * 8) < NSEQ;
      pv0 = vok ? *(const uint4*)(VgS + ko) : z4;
    }
    __syncthreads();
    ATTN_TILE_BODY(false)
  }
  {                                          // tile 28: mask keys >= 1800
    __syncthreads();
    *(uint4*)&Ks[sr][sc * 8] = pk0;
    *(uint4*)&Vs[sr][sc * 8] = pv0;
    __syncthreads();
    ATTN_TILE_BODY(true)
  }

#pragma unroll
  for (int r = 0; r < 4; ++r) {
    int qgA = q0 + wave * 16 + quad * 4 + r;
    if (qgA < NSEQ) {
      float inv = 1.f / lsaccA[r];
#pragma unroll
      for (int nt = 0; nt < 4; ++nt)
        out[(baseBN + qgA) * 512 + hh * 64 + nt * 16 + l16] = fp8(oA[nt][r] * inv);
    }
  }
}

// ---------------- head: reads COMPACT xm (row bi), patches gathered ----------------
__global__ __launch_bounds__(192)
void head_kernel(const f16* __restrict__ xm, const float* __restrict__ patches,
                 const int* __restrict__ mi, const float* __restrict__ Wt,
                 const float* __restrict__ bt, float* __restrict__ lossAcc) {
  int t = threadIdx.x;            // 192 = 6 pd * 32 lanes
  int pd = t / 32, sg = t % 32;
  float wt[16];
#pragma unroll
  for (int k = 0; k < 16; ++k) wt[k] = Wt[(sg * 16 + k) * 6 + pd];
  float btv = bt[pd];
  float accAll = 0.f;
  for (int rr = 0; rr < 32; ++rr) {
    int bi = blockIdx.x * 32 + rr;    // 0..7199
    int b = bi / NMASK;
    int idx = mi[bi];
    const f16x8* xr8 = (const f16x8*)(xm + (long)bi * DIM);
    float acc = 0.f;
#pragma unroll
    for (int j = 0; j < 2; ++j) {
      f16x8 xa = xr8[sg * 2 + j];
#pragma unroll
      for (int k2 = 0; k2 < 8; ++k2) acc += (float)xa[k2] * wt[j * 8 + k2];
    }
#pragma unroll
    for (int mk = 1; mk < 32; mk <<= 1) acc += __shfl_xor(acc, mk);
    if (sg == 0) {
      float pred = acc + btv;
      accAll += fabsf(pred - patches[((long)b * NSEQ + idx) * 6 + pd]);
    }
  }
  if (sg == 0) atomicAdd(lossAcc, accAll);
}

__global__ void finalize_kernel(const float* __restrict__ acc, float* __restrict__ out) {
  if (threadIdx.x == 0 && blockIdx.x == 0)
    out[0] = acc[0] * (1.0f / 38880000.0f);   // /(8*900*6) / 900
}

// ---------------- launcher ----------------
extern "C" void kernel_launch(void* const* d_in, const int* in_sizes, int n_in,
                              void* d_out, int out_size, void* d_ws, size_t ws_size,
                              hipStream_t stream) {
  (void)in_sizes; (void)n_in; (void)out_size; (void)ws_size;
  const float* img       = (const float*)d_in[0];
  const float* pos_table = (const float*)d_in[1];
  const float* val_table = (const float*)d_in[2];
  const float* patch_W   = (const float*)d_in[3];
  const float* patch_b   = (const float*)d_in[4];
  const float* mask_tok  = (const float*)d_in[5];
  const float* ln1_s     = (const float*)d_in[6];
  const float* ln1_b     = (const float*)d_in[7];
  const float* Wqkv      = (const float*)d_in[8];
  const float* bqkv      = (const float*)d_in[9];
  const float* Wo        = (const float*)d_in[10];
  const float* bo        = (const float*)d_in[11];
  const float* ln2_s     = (const float*)d_in[12];
  const float* ln2_b     = (const float*)d_in[13];
  const float* W1        = (const float*)d_in[14];
  const float* b1        = (const float*)d_in[15];
  const float* W2        = (const float*)d_in[16];
  const float* b2        = (const float*)d_in[17];
  const float* Wt        = (const float*)d_in[18];
  const float* bt        = (const float*)d_in[19];
  const int* valid_len   = (const int*)d_in[20];
  const int* mask_idx    = (const int*)d_in[21];

  char* p = (char*)d_ws;
  auto alloc = [&](size_t bytes) { char* r = p; p += (bytes + 511) & ~(size_t)511; return r; };
  float* patches = (float*)alloc((size_t)MROWS * 6 * 4);
  int*   maskf   = (int*)alloc((size_t)MROWS * 4);
  int*   grows   = (int*)alloc((size_t)MMASK * 4);
  float* lossAcc = (float*)alloc(256);
  f16*   x       = (f16*)alloc((size_t)MROWS * 512 * 2);
  f16*   xm      = (f16*)alloc((size_t)(MMASK + 128) * 512 * 2);   // compact masked rows (l=3)
  fp8*   h       = (fp8*)alloc((size_t)MROWS * 512 + 512);
  f16*   Vt      = (f16*)alloc((size_t)64 * 64 * 1800 * 2 + 512);  // +pad for prefetch overreach
  f16*   qkv     = (f16*)alloc((size_t)MROWS * 2048 * 2); // qkv f16 (1536) / hid fp8 (2048)
  fp8*   attn    = (fp8*)alloc((size_t)MROWS * 512);
  fp8*   WqT     = (fp8*)alloc((size_t)4 * 1536 * 512);
  fp8*   WoT     = (fp8*)alloc((size_t)4 * 512 * 512);
  fp8*   W1T     = (fp8*)alloc((size_t)4 * 2048 * 512);
  fp8*   W2T     = (fp8*)alloc((size_t)4 * 512 * 2048);
  fp8*   hid     = (fp8*)qkv;    // qkv dead after attn within a layer

  hipMemsetAsync(maskf, 0, (size_t)MROWS * 4, stream);
  hipMemsetAsync(lossAcc, 0, 4, stream);
  scatter_mask<<<29, 256, 0, stream>>>(mask_idx, maskf, grows);

  transposeW<<<dim3(48, 16, 4), dim3(32, 8), 0, stream>>>(Wqkv, WqT, 512, 1536);
  transposeW<<<dim3(16, 16, 4), dim3(32, 8), 0, stream>>>(Wo,  WoT, 512, 512);
  transposeW<<<dim3(64, 16, 4), dim3(32, 8), 0, stream>>>(W1,  W1T, 512, 2048);
  transposeW<<<dim3(16, 64, 4), dim3(32, 8), 0, stream>>>(W2,  W2T, 2048, 512);

  prep_kernel<<<dim3(1800, 8), 256, 0, stream>>>(img, pos_table, val_table, patch_W, patch_b,
                                                 mask_tok, valid_len, maskf, patches, x);

  for (int l = 0; l < 4; ++l) {
    ln_kernel<<<1800, 256, 0, stream>>>(x, ln1_s + l * 512, ln1_b + l * 512, h);
    // QKV: 256-row tile, 57x12 blocks, 512 threads
    gemm256_kernel<0><<<dim3(57 * 12), 512, 0, stream>>>((const u8*)h, (const u8*)(WqT + (size_t)l * 1536 * 512),
                                                         bqkv + l * 1536, qkv, nullptr, Vt,
                                                         MROWS, 1536, 512, 12);
    attn_kernel<<<dim3(960), 512, 0, stream>>>(qkv, Vt, attn);
    if (l < 3) {
      gemm8_kernel<1><<<dim3(4 * 113), 512, 0, stream>>>((const u8*)attn, (const u8*)(WoT + (size_t)l * 512 * 512),
                                                         bo + l * 512, x, x, nullptr, nullptr,
                                                         MROWS, 512, 512, 4);
      ln_kernel<<<1800, 256, 0, stream>>>(x, ln2_s + l * 512, ln2_b + l * 512, h);
      // W1: 256-row tile, 57x16 blocks
      gemm256_kernel<2><<<dim3(57 * 16), 512, 0, stream>>>((const u8*)h, (const u8*)(W1T + (size_t)l * 2048 * 512),
                                                           b1 + l * 2048, nullptr, hid, nullptr,
                                                           MROWS, 2048, 512, 16);
      gemm8_kernel<1><<<dim3(4 * 113), 512, 0, stream>>>((const u8*)hid, (const u8*)(W2T + (size_t)l * 512 * 2048),
                                                         b2 + l * 512, x, x, nullptr, nullptr,
                                                         MROWS, 512, 2048, 4);
    } else {
      // layer 3: only masked rows feed the loss -> compact to 7200 rows.
      gemm8_kernel<1><<<dim3(4 * 57), 512, 0, stream>>>((const u8*)attn, (const u8*)(WoT + (size_t)l * 512 * 512),
                                                        bo + l * 512, x, xm, nullptr, grows,
                                                        MMASK, 512, 512, 4);
      ln_kernel<<<900, 256, 0, stream>>>(xm, ln2_s + l * 512, ln2_b + l * 512, h);
      gemm256_kernel<2><<<dim3(29 * 16), 512, 0, stream>>>((const u8*)h, (const u8*)(W1T + (size_t)l * 2048 * 512),
                                                           b1 + l * 2048, nullptr, hid, nullptr,
                                                           MMASK, 2048, 512, 16);
      gemm8_kernel<1><<<dim3(4 * 57), 512, 0, stream>>>((const u8*)hid, (const u8*)(W2T + (size_t)l * 512 * 2048),
                                                        b2 + l * 512, xm, xm, nullptr, nullptr,
                                                        MMASK, 512, 2048, 4);
    }
  }

  head_kernel<<<225, 192, 0, stream>>>(xm, patches, mask_idx, Wt, bt, lossAcc);
  finalize_kernel<<<1, 64, 0, stream>>>(lossAcc, (float*)d_out);
}

// Round 15
// 1254.832 us; speedup vs baseline: 1.0159x; 1.0159x over previous
//
#include <hip/hip_runtime.h>
#include <hip/hip_fp8.h>
#include <cstdint>

typedef _Float16 f16;
typedef _Float16 f16x2 __attribute__((ext_vector_type(2)));
typedef _Float16 f16x4 __attribute__((ext_vector_type(4)));
typedef _Float16 f16x8 __attribute__((ext_vector_type(8)));
typedef float    f32x4 __attribute__((ext_vector_type(4)));
typedef __hip_fp8_e4m3 fp8;
typedef long     i64;
typedef unsigned char u8;

#define BATCH 8
#define NSEQ  1800
#define DIM   512
#define NMASK 900
#define MROWS 14400   // BATCH*NSEQ
#define MMASK 7200    // BATCH*NMASK

// ---------------- async 16B global->LDS (with fallback) ----------------
__device__ __forceinline__ void stage16(const void* g, void* lds_wave_base, int lane) {
#if __has_builtin(__builtin_amdgcn_global_load_lds)
  (void)lane;
  __builtin_amdgcn_global_load_lds((const __attribute__((address_space(1))) void*)g,
                                   (__attribute__((address_space(3))) void*)lds_wave_base,
                                   16, 0, 0);
#else
  ((uint4*)lds_wave_base)[lane] = *(const uint4*)g;
#endif
}

__device__ __forceinline__ float gelu_f(float x) {
  // tanh-approx gelu (jax.nn.gelu approximate=True)
  float x3 = x * x * x;
  float y  = 0.7978845608028654f * (x + 0.044715f * x3);
  float t;
  if (y > 15.f)       t = 1.f;
  else if (y < -15.f) t = -1.f;
  else { float e = __expf(2.f * y); t = (e - 1.f) / (e + 1.f); }
  return 0.5f * x * (1.f + t);
}

// ---------------- mask scatter (+ gathered row table for layer-3 compaction) ----------------
__global__ void scatter_mask(const int* __restrict__ mi, int* __restrict__ maskf,
                             int* __restrict__ grows) {
  int i = blockIdx.x * 256 + threadIdx.x;
  if (i < BATCH * NMASK) {
    int b = i / NMASK;
    int row = b * NSEQ + mi[i];
    maskf[row] = 1;
    grows[i] = row;
  }
}

// ---------------- weight transpose + fp8 convert: in[K,N] -> out[N,K] ----------------
__global__ void transposeW(const float* __restrict__ in, fp8* __restrict__ out, int K, int N) {
  long off = (long)blockIdx.z * K * N;
  const float* ip = in + off;
  fp8* op = out + off;
  __shared__ float tile[32][33];
  int n0 = blockIdx.x * 32, k0 = blockIdx.y * 32;
  int tx = threadIdx.x, ty = threadIdx.y;  // (32,8)
#pragma unroll
  for (int i = 0; i < 4; ++i)
    tile[ty + 8 * i][tx] = ip[(long)(k0 + ty + 8 * i) * N + n0 + tx];
  __syncthreads();
#pragma unroll
  for (int i = 0; i < 4; ++i)
    op[(long)(n0 + ty + 8 * i) * K + k0 + tx] = fp8(tile[tx][ty + 8 * i]);
}

// ---------------- patch embed + pos/val emb + mask token -> x0 (f16 residual) ----------------
__global__ __launch_bounds__(256)
void prep_kernel(const float* __restrict__ img, const float* __restrict__ pos_table,
                 const float* __restrict__ val_table, const float* __restrict__ patch_W,
                 const float* __restrict__ patch_b, const float* __restrict__ mask_tok,
                 const int* __restrict__ valid_len, const int* __restrict__ maskf,
                 float* __restrict__ patches, f16* __restrict__ x0) {
  int n = blockIdx.x;       // 0..1799
  int b = blockIdx.y;       // 0..7
  int t = threadIdx.x;
  __shared__ float p[6];
  int h = n / 75, ws = n % 75;
  if (t < 6) {
    int pp = t / 3, c = t % 3;
    float v = img[((b * 3 + c) * 24 + h) * 150 + ws * 2 + pp];
    p[t] = v;
    patches[((long)b * NSEQ + n) * 6 + t] = v;
  }
  __syncthreads();
  int vl = valid_len[b];
  if (vl == 150) vl = 149;
  int nv = (vl + 1) >> 1;          // ceil(vl/2)
  int seg = (ws < nv) ? 1 : 0;
  bool masked = maskf[b * NSEQ + n] != 0;
  for (int d = t; d < DIM; d += 256) {
    float pos = pos_table[(long)(n + 1) * DIM + d] + val_table[seg * DIM + d];
    float v;
    if (masked) {
      v = mask_tok[d] + pos;
    } else {
      float acc = patch_b[d] + pos;
#pragma unroll
      for (int j = 0; j < 6; ++j) acc += p[j] * patch_W[j * DIM + d];
      v = acc;
    }
    x0[((long)b * NSEQ + n) * DIM + d] = (f16)v;
  }
}

// ---------------- LayerNorm: 8 rows/block, 1 row/wave-pass, no LDS ----------------
__global__ __launch_bounds__(256)
void ln_kernel(const f16* __restrict__ x, const float* __restrict__ s,
               const float* __restrict__ bb, fp8* __restrict__ out) {
  const int t = threadIdx.x;
  const int wave = t >> 6, lane = t & 63;
  const int col = lane * 8;
  float sv[8], bv[8];
  {
    float4 s0 = *(const float4*)&s[col], s1 = *(const float4*)&s[col + 4];
    float4 b0 = *(const float4*)&bb[col], b1 = *(const float4*)&bb[col + 4];
    sv[0] = s0.x; sv[1] = s0.y; sv[2] = s0.z; sv[3] = s0.w;
    sv[4] = s1.x; sv[5] = s1.y; sv[6] = s1.z; sv[7] = s1.w;
    bv[0] = b0.x; bv[1] = b0.y; bv[2] = b0.z; bv[3] = b0.w;
    bv[4] = b1.x; bv[5] = b1.y; bv[6] = b1.z; bv[7] = b1.w;
  }
  long rowBase = (long)blockIdx.x * 8 + wave * 2;
#pragma unroll
  for (int rr = 0; rr < 2; ++rr) {
    long row = rowBase + rr;
    f16x8 v = *(const f16x8*)(x + row * DIM + col);
    float f[8], sum = 0.f, sq = 0.f;
#pragma unroll
    for (int j = 0; j < 8; ++j) { f[j] = (float)v[j]; sum += f[j]; sq += f[j] * f[j]; }
#pragma unroll
    for (int mk = 1; mk < 64; mk <<= 1) {
      sum += __shfl_xor(sum, mk);
      sq  += __shfl_xor(sq, mk);
    }
    float mean = sum * (1.f / DIM);
    float var  = sq * (1.f / DIM) - mean * mean;
    float rstd = rsqrtf(var + 1e-5f);
    fp8 o8[8];
#pragma unroll
    for (int j = 0; j < 8; ++j) o8[j] = fp8((f[j] - mean) * rstd * sv[j] + bv[j]);
    *(uint2*)&out[row * DIM + col] = *(const uint2*)o8;
  }
}

// ---------------- MFMA fp8 GEMM 128x128 (small-N full GEMMs + layer-3 compact) ----
// 256 threads / 4 waves, acc[4][4]: per-wave MFMA work per barrier is the
// amortization unit — R14 showed splitting the tile across 8 waves (half the
// per-wave work) regresses. Kept for Wo/W2 (N=512): 452 blocks ~1.8/CU gives
// inter-block drain overlap (R10 lesson). gidx: layer-3 compaction gather.
// EPI 1: bias + f16 residual -> f16.
template <int EPI>
__global__ __launch_bounds__(256)
void gemm8_kernel(const u8* __restrict__ A, const u8* __restrict__ Bt,
                  const float* __restrict__ bias, const f16* __restrict__ res,
                  f16* __restrict__ outH, fp8* __restrict__ out8,
                  const int* __restrict__ gidx,
                  int M, int N, int K, int gx) {
  __shared__ u8 As[8 * 128 * 16];   // 16 KB
  __shared__ u8 Bs[8 * 128 * 16];   // 16 KB
  const int tid  = threadIdx.x;
  const int wave = tid >> 6, lane = tid & 63;
  const int quad = lane >> 4, l16 = lane & 15;
  const int wm = wave >> 1, wn = wave & 1;

  const int nwg = (int)gridDim.x;
  const int q = nwg >> 3, rr = nwg & 7;
  const int xcd = (int)blockIdx.x & 7, idx = (int)blockIdx.x >> 3;
  const int wg = (xcd < rr ? xcd * (q + 1) : rr * (q + 1) + (xcd - rr) * q) + idx;
  const long rowBase = (long)(wg / gx) * 128;
  const long colBase = (long)(wg % gx) * 128;

  f32x4 acc[4][4];   // [ni][mi]
  f32x4 zero = {0.f, 0.f, 0.f, 0.f};
#pragma unroll
  for (int ni = 0; ni < 4; ++ni)
#pragma unroll
    for (int mi = 0; mi < 4; ++mi) acc[ni][mi] = zero;

  long rA0 = rowBase + lane;       if (rA0 > M - 1) rA0 = M - 1;
  long rA1 = rowBase + 64 + lane;  if (rA1 > M - 1) rA1 = M - 1;
  if (gidx) { rA0 = gidx[rA0]; rA1 = gidx[rA1]; }
  const u8* Arow0 = A + rA0 * K + wave * 16;
  const u8* Arow1 = A + rA1 * K + wave * 16;
  const u8* Brow0 = Bt + (colBase + lane) * K + wave * 16;
  const u8* Brow1 = Bt + (colBase + 64 + lane) * K + wave * 16;
  u8* AsC0 = As + wave * 2048;
  u8* AsC1 = AsC0 + 64 * 16;
  u8* AsC2 = As + (wave + 4) * 2048;
  u8* AsC3 = AsC2 + 64 * 16;
  u8* BsC0 = Bs + wave * 2048;
  u8* BsC1 = BsC0 + 64 * 16;
  u8* BsC2 = Bs + (wave + 4) * 2048;
  u8* BsC3 = BsC2 + 64 * 16;

  for (int kt = 0; kt < K; kt += 128) {
    __syncthreads();
    stage16(Arow0 + kt,      AsC0, lane);
    stage16(Arow1 + kt,      AsC1, lane);
    stage16(Arow0 + kt + 64, AsC2, lane);
    stage16(Arow1 + kt + 64, AsC3, lane);
    stage16(Brow0 + kt,      BsC0, lane);
    stage16(Brow1 + kt,      BsC1, lane);
    stage16(Brow0 + kt + 64, BsC2, lane);
    stage16(Brow1 + kt + 64, BsC3, lane);
    __syncthreads();
#pragma unroll
    for (int ks = 0; ks < 4; ++ks) {
      const int cb = (2 * ks + (quad >> 1)) * 2048 + (quad & 1) * 8;
      i64 af[4], bf[4];
#pragma unroll
      for (int mi = 0; mi < 4; ++mi)
        af[mi] = *(const i64*)&As[cb + (wm * 64 + mi * 16 + l16) * 16];
#pragma unroll
      for (int ni = 0; ni < 4; ++ni)
        bf[ni] = *(const i64*)&Bs[cb + (wn * 64 + ni * 16 + l16) * 16];
#pragma unroll
      for (int ni = 0; ni < 4; ++ni)
#pragma unroll
        for (int mi = 0; mi < 4; ++mi)
          acc[ni][mi] = __builtin_amdgcn_mfma_f32_16x16x32_fp8_fp8(bf[ni], af[mi], acc[ni][mi], 0, 0, 0);
    }
  }

#pragma unroll
  for (int mi = 0; mi < 4; ++mi) {
    long m = rowBase + wm * 64 + mi * 16 + l16;
    if (m < M) {
      long gm = gidx ? (long)gidx[m] : m;
#pragma unroll
      for (int ni = 0; ni < 4; ++ni) {
        long n = colBase + wn * 64 + ni * 16 + quad * 4;
        float4 bv = *(const float4*)&bias[n];
        f32x4 v = acc[ni][mi];
        v[0] += bv.x; v[1] += bv.y; v[2] += bv.z; v[3] += bv.w;
        long o = m * N + n;
        if (EPI == 1) {
          f16x4 rr4 = *(const f16x4*)&res[gm * N + n];
          f16x4 ov;
#pragma unroll
          for (int r = 0; r < 4; ++r) ov[r] = (f16)(v[r] + (float)rr4[r]);
          *(f16x4*)&outH[o] = ov;
        } else if (EPI == 2) {
          fp8 hv[4];
#pragma unroll
          for (int r = 0; r < 4; ++r) hv[r] = fp8(gelu_f(v[r]));
          *(uint32_t*)&out8[o] = *(const uint32_t*)hv;
        } else {
          f16x4 hv;
#pragma unroll
          for (int r = 0; r < 4; ++r) hv[r] = (f16)v[r];
          *(f16x4*)&outH[o] = hv;
        }
      }
    }
  }
}

// ---------------- MFMA fp8 GEMM 256x128, 8 waves (large-N GEMMs: QKV, W1) ----
// Only used where grid >= ~2x CU count (QKV: 684 blocks, W1: 912 blocks).
// EPI 0: bias -> f16 (+outV: V-cols n>=1024 transposed to Vt);
// EPI 2: bias + gelu -> fp8.
template <int EPI>
__global__ __launch_bounds__(512)
void gemm256_kernel(const u8* __restrict__ A, const u8* __restrict__ Bt,
                    const float* __restrict__ bias,
                    f16* __restrict__ outH, fp8* __restrict__ out8, f16* __restrict__ outV,
                    int M, int N, int K, int gx) {
  __shared__ u8 As[8 * 256 * 16];   // 32 KB
  __shared__ u8 Bs[8 * 128 * 16];   // 16 KB
  const int tid  = threadIdx.x;
  const int wave = tid >> 6, lane = tid & 63;
  const int quad = lane >> 4, l16 = lane & 15;
  const int wm = wave >> 1, wn = wave & 1;   // wm 0..3, wn 0..1

  const int nwg = (int)gridDim.x;
  const int q = nwg >> 3, rr = nwg & 7;
  const int xcd = (int)blockIdx.x & 7, idx = (int)blockIdx.x >> 3;
  const int wg = (xcd < rr ? xcd * (q + 1) : rr * (q + 1) + (xcd - rr) * q) + idx;
  const long rowBase = (long)(wg / gx) * 256;
  const long colBase = (long)(wg % gx) * 128;

  f32x4 acc[4][4];   // [ni][mi]
  f32x4 zero = {0.f, 0.f, 0.f, 0.f};
#pragma unroll
  for (int ni = 0; ni < 4; ++ni)
#pragma unroll
    for (int mi = 0; mi < 4; ++mi) acc[ni][mi] = zero;

  const u8* ArowP[4];
#pragma unroll
  for (int i = 0; i < 4; ++i) {
    long r = rowBase + i * 64 + lane;
    if (r > M - 1) r = M - 1;
    ArowP[i] = A + r * K + wave * 16;
  }
  const u8* BrowP[2];
#pragma unroll
  for (int i = 0; i < 2; ++i)
    BrowP[i] = Bt + (colBase + i * 64 + lane) * K + wave * 16;
  u8* AsD = As + wave * 4096;
  u8* BsD = Bs + wave * 2048;

  for (int kt = 0; kt < K; kt += 128) {
    __syncthreads();
#pragma unroll
    for (int i = 0; i < 4; ++i)
      stage16(ArowP[i] + kt, AsD + i * 1024, lane);
#pragma unroll
    for (int i = 0; i < 2; ++i)
      stage16(BrowP[i] + kt, BsD + i * 1024, lane);
    __syncthreads();
#pragma unroll
    for (int ks = 0; ks < 4; ++ks) {
      const int c16 = 2 * ks + (quad >> 1);
      const int cbA = c16 * 4096 + (quad & 1) * 8;
      const int cbB = c16 * 2048 + (quad & 1) * 8;
      i64 af[4], bf[4];
#pragma unroll
      for (int mi = 0; mi < 4; ++mi)
        af[mi] = *(const i64*)&As[cbA + (wm * 64 + mi * 16 + l16) * 16];
#pragma unroll
      for (int ni = 0; ni < 4; ++ni)
        bf[ni] = *(const i64*)&Bs[cbB + (wn * 64 + ni * 16 + l16) * 16];
#pragma unroll
      for (int ni = 0; ni < 4; ++ni)
#pragma unroll
        for (int mi = 0; mi < 4; ++mi)
          acc[ni][mi] = __builtin_amdgcn_mfma_f32_16x16x32_fp8_fp8(bf[ni], af[mi], acc[ni][mi], 0, 0, 0);
    }
  }

  // ---- fused V-transpose path (QKV GEMM, V columns) ----
  if (EPI == 0 && outV != nullptr && colBase >= 1024) {
    const int hh = (int)((colBase - 1024) >> 6) + wn;   // 0..7
#pragma unroll
    for (int mi = 0; mi < 4; ++mi) {
      long m = rowBase + wm * 64 + mi * 16 + l16;
      if (m < M) {
        int b = (int)m / NSEQ;
        int key = (int)m - b * NSEQ;
        f16* vdst = outV + ((long)(b * 8 + hh) * 64) * NSEQ + key;
#pragma unroll
        for (int ni = 0; ni < 4; ++ni) {
          long n = colBase + wn * 64 + ni * 16 + quad * 4;
          float4 bv = *(const float4*)&bias[n];
          f32x4 v = acc[ni][mi];
#pragma unroll
          for (int r = 0; r < 4; ++r)
            vdst[(long)(ni * 16 + quad * 4 + r) * NSEQ] = (f16)(v[r] + (&bv.x)[r]);
        }
      }
    }
    return;
  }

#pragma unroll
  for (int mi = 0; mi < 4; ++mi) {
    long m = rowBase + wm * 64 + mi * 16 + l16;
    if (m < M) {
#pragma unroll
      for (int ni = 0; ni < 4; ++ni) {
        long n = colBase + wn * 64 + ni * 16 + quad * 4;
        float4 bv = *(const float4*)&bias[n];
        f32x4 v = acc[ni][mi];
        v[0] += bv.x; v[1] += bv.y; v[2] += bv.z; v[3] += bv.w;
        long o = m * N + n;
        if (EPI == 2) {
          fp8 hv[4];
#pragma unroll
          for (int r = 0; r < 4; ++r) hv[r] = fp8(gelu_f(v[r]));
          *(uint32_t*)&out8[o] = *(const uint32_t*)hv;
        } else {
          f16x4 hv;
#pragma unroll
          for (int r = 0; r < 4; ++r) hv[r] = (f16)v[r];
          *(f16x4*)&outH[o] = hv;
        }
      }
    }
  }
}

// ---------------- MFMA flash attention v8b: 8 waves x 16 q-rows (R13 verified) ----
#define ATTN_TILE_BODY(MASKV)                                                           \
  {                                                                                     \
    _Pragma("unroll")                                                                   \
    for (int n = 0; n < 4; ++n) {                                                       \
      f16x8 b0 = *(const f16x8*)&Ks[n * 16 + l16][quad * 8];                            \
      f16x8 b1 = *(const f16x8*)&Ks[n * 16 + l16][32 + quad * 8];                       \
      f32x4 zz = {0.f, 0.f, 0.f, 0.f};                                                  \
      zz = __builtin_amdgcn_mfma_f32_16x16x32_f16(qfA0, b0, zz, 0, 0, 0);               \
      zz = __builtin_amdgcn_mfma_f32_16x16x32_f16(qfA1, b1, zz, 0, 0, 0);               \
      bool bad = (MASKV) && (n > 0 || l16 >= 8);                                        \
      _Pragma("unroll")                                                                 \
      for (int r = 0; r < 4; ++r) {                                                     \
        float pp = exp2f(fmaf(zz[r], K1, -8.f));                                        \
        if (bad) pp = 0.f;                                                              \
        Ps[wave * 16 + quad * 4 + r][(n * 16 + l16) ^ (quad << 3)] = (f16)pp;           \
      }                                                                                 \
    }                                                                                   \
    {                                                                                   \
      f16x8 pa0 = *(const f16x8*)&Ps[wave * 16 + l16][pswz];                            \
      f16x8 pa1 = *(const f16x8*)&Ps[wave * 16 + l16][32 + pswz];                       \
      __builtin_amdgcn_s_setprio(1);                                                    \
      _Pragma("unroll")                                                                 \
      for (int nt = 0; nt < 4; ++nt) {                                                  \
        f16x8 vb0 = *(const f16x8*)&Vs[nt * 16 + l16][quad * 8];                        \
        f16x8 vb1 = *(const f16x8*)&Vs[nt * 16 + l16][32 + quad * 8];                   \
        oA[nt] = __builtin_amdgcn_mfma_f32_16x16x32_f16(pa0, vb0, oA[nt], 0, 0, 0);     \
        oA[nt] = __builtin_amdgcn_mfma_f32_16x16x32_f16(pa1, vb1, oA[nt], 0, 0, 0);     \
      }                                                                                 \
      lsaccA = __builtin_amdgcn_mfma_f32_16x16x32_f16(pa0, onesf, lsaccA, 0, 0, 0);     \
      lsaccA = __builtin_amdgcn_mfma_f32_16x16x32_f16(pa1, onesf, lsaccA, 0, 0, 0);     \
      __builtin_amdgcn_s_setprio(0);                                                    \
    }                                                                                   \
  }

__global__ __launch_bounds__(512, 4)
void attn_kernel(const f16* __restrict__ qkv, const f16* __restrict__ Vt,
                 fp8* __restrict__ out) {
  const int g = blockIdx.x;                  // 0..959
  const int hi = g / 120, rem = g % 120;     // 120 = 15 q-tiles * 8
  const int qt = rem >> 3;                   // 0..14
  const int bh = hi * 8 + (rem & 7);         // g%8 == bh&7 -> one XCD per bh
  const int b = bh >> 3, hh = bh & 7;
  const int t = threadIdx.x;                 // 0..511
  const int wave = t >> 6, lane = t & 63;    // wave 0..7
  const int quad = lane >> 4, l16 = lane & 15;
  const int q0 = qt * 128;
  const long baseBN = (long)b * NSEQ;
  const float K1 = 0.18033688011112042f;     // 0.125 * log2(e)
  const int pswz = ((quad ^ (l16 >> 2)) << 3);   // P-read swizzled col base
  const f16x8 onesf = {(f16)1.f, (f16)1.f, (f16)1.f, (f16)1.f,
                       (f16)1.f, (f16)1.f, (f16)1.f, (f16)1.f};

  __shared__ f16 Ks[64][80];    // [key][dh]
  __shared__ f16 Vs[64][80];    // [dh][key]
  __shared__ f16 Ps[128][80];   // [q%128][key], rows wave-private

  int qrA = q0 + wave * 16 + l16; if (qrA > NSEQ - 1) qrA = NSEQ - 1;
  const f16* QpA = qkv + (baseBN + qrA) * 1536 + hh * 64 + quad * 8;
  f16x8 qfA0 = *(const f16x8*)(QpA);
  f16x8 qfA1 = *(const f16x8*)(QpA + 32);

  f32x4 oA[4];
  f32x4 lsaccA = {0.f, 0.f, 0.f, 0.f};
#pragma unroll
  for (int nt = 0; nt < 4; ++nt) oA[nt] = f32x4{0, 0, 0, 0};

  const f16* Kg = qkv + baseBN * 1536 + hh * 64 + 512;
  const f16* Vg = Vt + (long)bh * 64 * 1800;
  const int sr = t >> 3, sc = t & 7;         // sr 0..63, sc 0..7
  const uint4 z4 = {0u, 0u, 0u, 0u};

  const f16* KgS = Kg + (long)sr * 1536 + sc * 8;
  const f16* VgS = Vg + (long)sr * 1800 + sc * 8;

  uint4 pk0 = *(const uint4*)(KgS);
  uint4 pv0 = *(const uint4*)(VgS);

  for (int kt = 0; kt < 28; ++kt) {          // tiles 0..27: no key masking
    __syncthreads();
    *(uint4*)&Ks[sr][sc * 8] = pk0;
    *(uint4*)&Vs[sr][sc * 8] = pv0;
    {
      long ko = (long)(kt + 1) * 64;
      pk0 = *(const uint4*)(KgS + ko * 1536);
      bool vok = (ko + sc * 8) < NSEQ;
      pv0 = vok ? *(const uint4*)(VgS + ko) : z4;
    }
    __syncthreads();
    ATTN_TILE_BODY(false)
  }
  {                                          // tile 28: mask keys >= 1800
    __syncthreads();
    *(uint4*)&Ks[sr][sc * 8] = pk0;
    *(uint4*)&Vs[sr][sc * 8] = pv0;
    __syncthreads();
    ATTN_TILE_BODY(true)
  }

#pragma unroll
  for (int r = 0; r < 4; ++r) {
    int qgA = q0 + wave * 16 + quad * 4 + r;
    if (qgA < NSEQ) {
      float inv = 1.f / lsaccA[r];
#pragma unroll
      for (int nt = 0; nt < 4; ++nt)
        out[(baseBN + qgA) * 512 + hh * 64 + nt * 16 + l16] = fp8(oA[nt][r] * inv);
    }
  }
}

// ---------------- head: reads COMPACT xm (row bi), patches gathered ----------------
__global__ __launch_bounds__(192)
void head_kernel(const f16* __restrict__ xm, const float* __restrict__ patches,
                 const int* __restrict__ mi, const float* __restrict__ Wt,
                 const float* __restrict__ bt, float* __restrict__ lossAcc) {
  int t = threadIdx.x;            // 192 = 6 pd * 32 lanes
  int pd = t / 32, sg = t % 32;
  float wt[16];
#pragma unroll
  for (int k = 0; k < 16; ++k) wt[k] = Wt[(sg * 16 + k) * 6 + pd];
  float btv = bt[pd];
  float accAll = 0.f;
  for (int rr = 0; rr < 32; ++rr) {
    int bi = blockIdx.x * 32 + rr;    // 0..7199
    int b = bi / NMASK;
    int idx = mi[bi];
    const f16x8* xr8 = (const f16x8*)(xm + (long)bi * DIM);
    float acc = 0.f;
#pragma unroll
    for (int j = 0; j < 2; ++j) {
      f16x8 xa = xr8[sg * 2 + j];
#pragma unroll
      for (int k2 = 0; k2 < 8; ++k2) acc += (float)xa[k2] * wt[j * 8 + k2];
    }
#pragma unroll
    for (int mk = 1; mk < 32; mk <<= 1) acc += __shfl_xor(acc, mk);
    if (sg == 0) {
      float pred = acc + btv;
      accAll += fabsf(pred - patches[((long)b * NSEQ + idx) * 6 + pd]);
    }
  }
  if (sg == 0) atomicAdd(lossAcc, accAll);
}

__global__ void finalize_kernel(const float* __restrict__ acc, float* __restrict__ out) {
  if (threadIdx.x == 0 && blockIdx.x == 0)
    out[0] = acc[0] * (1.0f / 38880000.0f);   // /(8*900*6) / 900
}

// ---------------- launcher ----------------
extern "C" void kernel_launch(void* const* d_in, const int* in_sizes, int n_in,
                              void* d_out, int out_size, void* d_ws, size_t ws_size,
                              hipStream_t stream) {
  (void)in_sizes; (void)n_in; (void)out_size; (void)ws_size;
  const float* img       = (const float*)d_in[0];
  const float* pos_table = (const float*)d_in[1];
  const float* val_table = (const float*)d_in[2];
  const float* patch_W   = (const float*)d_in[3];
  const float* patch_b   = (const float*)d_in[4];
  const float* mask_tok  = (const float*)d_in[5];
  const float* ln1_s     = (const float*)d_in[6];
  const float* ln1_b     = (const float*)d_in[7];
  const float* Wqkv      = (const float*)d_in[8];
  const float* bqkv      = (const float*)d_in[9];
  const float* Wo        = (const float*)d_in[10];
  const float* bo        = (const float*)d_in[11];
  const float* ln2_s     = (const float*)d_in[12];
  const float* ln2_b     = (const float*)d_in[13];
  const float* W1        = (const float*)d_in[14];
  const float* b1        = (const float*)d_in[15];
  const float* W2        = (const float*)d_in[16];
  const float* b2        = (const float*)d_in[17];
  const float* Wt        = (const float*)d_in[18];
  const float* bt        = (const float*)d_in[19];
  const int* valid_len   = (const int*)d_in[20];
  const int* mask_idx    = (const int*)d_in[21];

  char* p = (char*)d_ws;
  auto alloc = [&](size_t bytes) { char* r = p; p += (bytes + 511) & ~(size_t)511; return r; };
  float* patches = (float*)alloc((size_t)MROWS * 6 * 4);
  int*   maskf   = (int*)alloc((size_t)MROWS * 4);
  int*   grows   = (int*)alloc((size_t)MMASK * 4);
  float* lossAcc = (float*)alloc(256);
  f16*   x       = (f16*)alloc((size_t)MROWS * 512 * 2);
  f16*   xm      = (f16*)alloc((size_t)(MMASK + 128) * 512 * 2);   // compact masked rows (l=3)
  fp8*   h       = (fp8*)alloc((size_t)MROWS * 512 + 512);
  f16*   Vt      = (f16*)alloc((size_t)64 * 64 * 1800 * 2 + 512);  // +pad for prefetch overreach
  f16*   qkv     = (f16*)alloc((size_t)MROWS * 2048 * 2); // qkv f16 (1536) / hid fp8 (2048)
  fp8*   attn    = (fp8*)alloc((size_t)MROWS * 512);
  fp8*   WqT     = (fp8*)alloc((size_t)4 * 1536 * 512);
  fp8*   WoT     = (fp8*)alloc((size_t)4 * 512 * 512);
  fp8*   W1T     = (fp8*)alloc((size_t)4 * 2048 * 512);
  fp8*   W2T     = (fp8*)alloc((size_t)4 * 512 * 2048);
  fp8*   hid     = (fp8*)qkv;    // qkv dead after attn within a layer

  hipMemsetAsync(maskf, 0, (size_t)MROWS * 4, stream);
  hipMemsetAsync(lossAcc, 0, 4, stream);
  scatter_mask<<<29, 256, 0, stream>>>(mask_idx, maskf, grows);

  transposeW<<<dim3(48, 16, 4), dim3(32, 8), 0, stream>>>(Wqkv, WqT, 512, 1536);
  transposeW<<<dim3(16, 16, 4), dim3(32, 8), 0, stream>>>(Wo,  WoT, 512, 512);
  transposeW<<<dim3(64, 16, 4), dim3(32, 8), 0, stream>>>(W1,  W1T, 512, 2048);
  transposeW<<<dim3(16, 64, 4), dim3(32, 8), 0, stream>>>(W2,  W2T, 2048, 512);

  prep_kernel<<<dim3(1800, 8), 256, 0, stream>>>(img, pos_table, val_table, patch_W, patch_b,
                                                 mask_tok, valid_len, maskf, patches, x);

  for (int l = 0; l < 4; ++l) {
    ln_kernel<<<1800, 256, 0, stream>>>(x, ln1_s + l * 512, ln1_b + l * 512, h);
    // QKV: 256-row tile, 57x12 blocks, 512 threads
    gemm256_kernel<0><<<dim3(57 * 12), 512, 0, stream>>>((const u8*)h, (const u8*)(WqT + (size_t)l * 1536 * 512),
                                                         bqkv + l * 1536, qkv, nullptr, Vt,
                                                         MROWS, 1536, 512, 12);
    attn_kernel<<<dim3(960), 512, 0, stream>>>(qkv, Vt, attn);
    if (l < 3) {
      gemm8_kernel<1><<<dim3(4 * 113), 256, 0, stream>>>((const u8*)attn, (const u8*)(WoT + (size_t)l * 512 * 512),
                                                         bo + l * 512, x, x, nullptr, nullptr,
                                                         MROWS, 512, 512, 4);
      ln_kernel<<<1800, 256, 0, stream>>>(x, ln2_s + l * 512, ln2_b + l * 512, h);
      // W1: 256-row tile, 57x16 blocks
      gemm256_kernel<2><<<dim3(57 * 16), 512, 0, stream>>>((const u8*)h, (const u8*)(W1T + (size_t)l * 2048 * 512),
                                                           b1 + l * 2048, nullptr, hid, nullptr,
                                                           MROWS, 2048, 512, 16);
      gemm8_kernel<1><<<dim3(4 * 113), 256, 0, stream>>>((const u8*)hid, (const u8*)(W2T + (size_t)l * 512 * 2048),
                                                         b2 + l * 512, x, x, nullptr, nullptr,
                                                         MROWS, 512, 2048, 4);
    } else {
      // layer 3: only masked rows feed the loss -> compact to 7200 rows.
      gemm8_kernel<1><<<dim3(4 * 57), 256, 0, stream>>>((const u8*)attn, (const u8*)(WoT + (size_t)l * 512 * 512),
                                                        bo + l * 512, x, xm, nullptr, grows,
                                                        MMASK, 512, 512, 4);
      ln_kernel<<<900, 256, 0, stream>>>(xm, ln2_s + l * 512, ln2_b + l * 512, h);
      gemm256_kernel<2><<<dim3(29 * 16), 512, 0, stream>>>((const u8*)h, (const u8*)(W1T + (size_t)l * 2048 * 512),
                                                           b1 + l * 2048, nullptr, hid, nullptr,
                                                           MMASK, 2048, 512, 16);
      gemm8_kernel<1><<<dim3(4 * 57), 256, 0, stream>>>((const u8*)hid, (const u8*)(W2T + (size_t)l * 512 * 2048),
                                                        b2 + l * 512, xm, xm, nullptr, nullptr,
                                                        MMASK, 512, 2048, 4);
    }
  }

  head_kernel<<<225, 192, 0, stream>>>(xm, patches, mask_idx, Wt, bt, lossAcc);
  finalize_kernel<<<1, 64, 0, stream>>>(lossAcc, (float*)d_out);
}